// Round 5
// baseline (1352.655 us; speedup 1.0000x reference)
//
#include <hip/hip_runtime.h>
#include <hip/hip_bf16.h>
#include <cstdint>
#include <cstddef>

typedef __hip_bfloat16 bf16;

#define NN 50000
#define NE 400000
#define SW 224   // intermediate row stride (elements)

struct PTab {
    const void* p[17];
    int n[17];
    int o[17];
};

__device__ __forceinline__ float bf2f(unsigned short u) {
    return __uint_as_float(((unsigned)u) << 16);
}
__device__ __forceinline__ unsigned short f2bf(float f) {
    __hip_bfloat16 h = __float2bfloat16(f);
    return *reinterpret_cast<unsigned short*>(&h);
}
__device__ __forceinline__ float fin(float v) {
    return (v == v && v > -1e30f && v < 1e30f) ? v : 0.0f;
}

// ---- probe dtypes: flags[t]=1 if tensor t is fp32, 0 if bf16 (t=0..16);
// flags[17]=1 if edge_index is int32 layout, 0 if int64 ----
__global__ void k_probe(PTab tab, const int* __restrict__ ei, int* __restrict__ flags) {
    __shared__ int zc, bc, sAny;
    for (int t = 0; t < 17; ++t) {
        if (threadIdx.x == 0) { zc = 0; bc = 0; }
        __syncthreads();
        int words = tab.n[t] >> 1;          // in-bounds under either dtype
        if (words > 256) words = 256;
        if ((int)threadIdx.x < words) {
            unsigned w = ((const unsigned*)tab.p[t])[threadIdx.x];
            if (w == 0u) atomicAdd(&zc, 1);
            else {
                int e = (w >> 7) & 0xFF;    // low halfword's bf16 exponent field
                if (e >= 100 && e <= 140) atomicAdd(&bc, 1);
            }
        }
        __syncthreads();
        if (threadIdx.x == 0) {
            int nz = words - zc;
            flags[t] = (nz == 0 || 2 * bc >= nz) ? 0 : 1;  // all-zero -> safe bf16 read
        }
        __syncthreads();
    }
    if (threadIdx.x == 0) sAny = 0;
    __syncthreads();
    int any = 0;
    for (int i = threadIdx.x; i < 2048; i += 256) any |= ei[2 * i + 1];
    if (any) sAny = 1;     // benign race
    __syncthreads();
    if (threadIdx.x == 0) flags[17] = sAny;
}

// ---- convert all 16 weight/bias tensors to fp32 wflat (sanitized) ----
__global__ void k_wconv(PTab tab, const int* __restrict__ flags, float* __restrict__ wflat) {
    int gid = blockIdx.x * blockDim.x + threadIdx.x;
    int gs = gridDim.x * blockDim.x;
    for (int t = 1; t < 17; ++t) {
        int n = tab.n[t];
        const void* s = tab.p[t];
        int f = flags[t];
        float* d = wflat + tab.o[t];
        for (int i = gid; i < n; i += gs)
            d[i] = fin(f ? ((const float*)s)[i] : bf2f(((const unsigned short*)s)[i]));
    }
}

__global__ void k_repack(const int* __restrict__ ei, const int* __restrict__ flags,
                         int* __restrict__ src, int* __restrict__ dst) {
    int e = blockIdx.x * blockDim.x + threadIdx.x;
    if (e >= NE) return;
    int s, d;
    if (flags[17]) { s = ei[e]; d = ei[NE + e]; }
    else           { s = ei[2 * e]; d = ei[2 * (NE + e)]; }   // int64 low words
    src[e] = min(max(s, 0), NN - 1);
    dst[e] = min(max(d, 0), NN - 1);
}

__global__ void k_zero(int* __restrict__ p, int n) {
    int i = blockIdx.x * blockDim.x + threadIdx.x;
    if (i < n) p[i] = 0;
}

__global__ void k_count(const int* __restrict__ dst, int* __restrict__ deg) {
    int e = blockIdx.x * blockDim.x + threadIdx.x;
    if (e < NE) atomicAdd(&deg[dst[e]], 1);
}

__global__ void k_scan1(const int* __restrict__ deg, int* __restrict__ rowp,
                        int* __restrict__ part) {
    __shared__ int s[512];
    int tid = threadIdx.x, i = blockIdx.x * 512 + tid;
    int v = (i < NN) ? deg[i] : 0;
    s[tid] = v;
    __syncthreads();
    for (int off = 1; off < 512; off <<= 1) {
        int t = (tid >= off) ? s[tid - off] : 0;
        __syncthreads();
        s[tid] += t;
        __syncthreads();
    }
    if (i < NN) rowp[i] = s[tid] - v;
    if (tid == 511) part[blockIdx.x] = s[511];
}
__global__ void k_scan2(int* __restrict__ part, int nb) {
    __shared__ int s[128];
    int tid = threadIdx.x;
    int v = (tid < nb) ? part[tid] : 0;
    s[tid] = v;
    __syncthreads();
    for (int off = 1; off < 128; off <<= 1) {
        int t = (tid >= off) ? s[tid - off] : 0;
        __syncthreads();
        s[tid] += t;
        __syncthreads();
    }
    if (tid < nb) part[tid] = s[tid] - v;
}
__global__ void k_scan3(int* __restrict__ rowp, const int* __restrict__ part,
                        const int* __restrict__ deg, float* __restrict__ dinv) {
    int i = blockIdx.x * blockDim.x + threadIdx.x;
    if (i < NN) {
        rowp[i] += part[i >> 9];
        dinv[i] = rsqrtf((float)deg[i] + 1.0f);
    }
    if (i == 0) rowp[NN] = NE;
}

__global__ void k_fill(const int* __restrict__ src, const int* __restrict__ dst,
                       const int* __restrict__ rowp, int* __restrict__ cursor,
                       int* __restrict__ colv) {
    int e = blockIdx.x * blockDim.x + threadIdx.x;
    if (e >= NE) return;
    int d = dst[e];
    int p = atomicAdd(&cursor[d], 1);
    colv[rowp[d] + p] = src[e];
}

// ---- bufA = x * dinv (storage fp32 or bf16 per sf) ----
__global__ void k_xin(const void* __restrict__ x, const int* __restrict__ flags,
                      const float* __restrict__ dinv, void* __restrict__ bufA, int sf) {
    int t = blockIdx.x * blockDim.x + threadIdx.x;
    if (t >= NN * 16) return;
    int i = t >> 4, c = (t & 15) * 8;
    float d = dinv[i];
    float v[8];
    if (flags[0]) {
        const float* xp = (const float*)x + (size_t)i * 128 + c;
        #pragma unroll
        for (int j = 0; j < 8; ++j) v[j] = fin(xp[j]) * d;
    } else {
        const unsigned short* xp = (const unsigned short*)x + (size_t)i * 128 + c;
        #pragma unroll
        for (int j = 0; j < 8; ++j) v[j] = fin(bf2f(xp[j])) * d;
    }
    if (sf) {
        float* o = (float*)bufA + (size_t)i * SW + c;
        #pragma unroll
        for (int j = 0; j < 8; ++j) o[j] = v[j];
    } else {
        unsigned short ob[8];
        #pragma unroll
        for (int j = 0; j < 8; ++j) ob[j] = f2bf(v[j]);
        *(uint4*)((unsigned short*)bufA + (size_t)i * SW + c) = *(uint4*)ob;
    }
}

// ---- CSR gather: out[i] = dinv[i] * (in[i] + sum_j in[colv[j]]) ----
__global__ void k_gather(const void* __restrict__ in, int istride,
                         void* __restrict__ out, int ostride, int kpad8,
                         const int* __restrict__ rowp, const int* __restrict__ colv,
                         const float* __restrict__ dinv, int sf) {
    int node = blockIdx.x * 4 + (threadIdx.x >> 6);
    int lane = threadIdx.x & 63;
    if (node >= NN) return;
    bool on = lane < kpad8;
    float a[8] = {};
    const int beg = rowp[node], end = rowp[node + 1];
    if (on) {
        if (sf) {
            const float* p = (const float*)in + (size_t)node * istride + lane * 8;
            #pragma unroll
            for (int j = 0; j < 8; ++j) a[j] = p[j];
        } else {
            uint4 q = *(const uint4*)((const unsigned short*)in + (size_t)node * istride + lane * 8);
            unsigned v[4] = {q.x, q.y, q.z, q.w};
            #pragma unroll
            for (int j = 0; j < 4; ++j) { a[2 * j] = bf2f(v[j] & 0xFFFF); a[2 * j + 1] = bf2f(v[j] >> 16); }
        }
    }
    for (int j = beg; j < end; ++j) {
        int s = colv[j];
        if (on) {
            if (sf) {
                const float* p = (const float*)in + (size_t)s * istride + lane * 8;
                #pragma unroll
                for (int t = 0; t < 8; ++t) a[t] += p[t];
            } else {
                uint4 q = *(const uint4*)((const unsigned short*)in + (size_t)s * istride + lane * 8);
                unsigned v[4] = {q.x, q.y, q.z, q.w};
                #pragma unroll
                for (int t = 0; t < 4; ++t) { a[2 * t] += bf2f(v[t] & 0xFFFF); a[2 * t + 1] += bf2f(v[t] >> 16); }
            }
        }
    }
    if (on) {
        float d = dinv[node];
        if (sf) {
            float* o = (float*)out + (size_t)node * ostride + lane * 8;
            #pragma unroll
            for (int j = 0; j < 8; ++j) o[j] = a[j] * d;
        } else {
            unsigned short ob[8];
            #pragma unroll
            for (int j = 0; j < 8; ++j) ob[j] = f2bf(a[j] * d);
            *(uint4*)((unsigned short*)out + (size_t)node * ostride + lane * 8) = *(uint4*)ob;
        }
    }
}

// ---- GEMM: out = post(A @ W + b); A storage per sf; W,b fp32.
// fmode 0: intermediate (relu * dinv, storage sf); fmode 1: FINAL fp32 (sigmoid) ----
#define GBM 128
#define GBK 16
__launch_bounds__(256)
__global__ void k_gemm(const void* __restrict__ A, int istride,
                       const float* __restrict__ W, const float* __restrict__ bias,
                       const float* __restrict__ dinv,
                       void* __restrict__ out, int ostride,
                       int K, int M, int Mpad, int sf, int fmode) {
    __shared__ float sA[GBK][GBM + 4];
    __shared__ float sB[GBK][GBM + 4];
    const int tid = threadIdx.x;
    const int tx = tid & 15, ty = tid >> 4;
    const int row0 = blockIdx.x * GBM;
    const int col0 = blockIdx.y * GBM;
    float acc[8][8] = {};

    const int arow = tid >> 1;
    const int akof = (tid & 1) * 8;
    const int bk   = tid >> 4;
    const int bnof = (tid & 15) * 8;
    int arowg = row0 + arow; if (arowg >= NN) arowg = NN - 1;

    for (int k0 = 0; k0 < K; k0 += GBK) {
        if (sf) {
            const float* ap = (const float*)A + (size_t)arowg * istride + k0 + akof;
            float4 q0 = *(const float4*)ap;
            float4 q1 = *(const float4*)(ap + 4);
            sA[akof + 0][arow] = q0.x; sA[akof + 1][arow] = q0.y;
            sA[akof + 2][arow] = q0.z; sA[akof + 3][arow] = q0.w;
            sA[akof + 4][arow] = q1.x; sA[akof + 5][arow] = q1.y;
            sA[akof + 6][arow] = q1.z; sA[akof + 7][arow] = q1.w;
        } else {
            uint4 q = *(const uint4*)((const unsigned short*)A + (size_t)arowg * istride + k0 + akof);
            unsigned v[4] = {q.x, q.y, q.z, q.w};
            #pragma unroll
            for (int j = 0; j < 4; ++j) {
                sA[akof + 2 * j][arow]     = bf2f(v[j] & 0xFFFF);
                sA[akof + 2 * j + 1][arow] = bf2f(v[j] >> 16);
            }
        }
        {
            int kg = k0 + bk;
            bool kok = kg < K;
            const float* wrow = W + (size_t)kg * M;
            #pragma unroll
            for (int p = 0; p < 8; ++p) {
                int ng = col0 + bnof + p;
                sB[bk][bnof + p] = (kok && ng < M) ? wrow[ng] : 0.0f;
            }
        }
        __syncthreads();
        #pragma unroll
        for (int kk = 0; kk < GBK; ++kk) {
            const float4 a0 = *(const float4*)&sA[kk][ty * 8];
            const float4 a1 = *(const float4*)&sA[kk][ty * 8 + 4];
            const float4 b0 = *(const float4*)&sB[kk][tx * 8];
            const float4 b1 = *(const float4*)&sB[kk][tx * 8 + 4];
            float av[8] = {a0.x, a0.y, a0.z, a0.w, a1.x, a1.y, a1.z, a1.w};
            float bv[8] = {b0.x, b0.y, b0.z, b0.w, b1.x, b1.y, b1.z, b1.w};
            #pragma unroll
            for (int r = 0; r < 8; ++r)
                #pragma unroll
                for (int c = 0; c < 8; ++c)
                    acc[r][c] = fmaf(av[r], bv[c], acc[r][c]);
        }
        __syncthreads();
    }

    #pragma unroll
    for (int rr = 0; rr < 8; ++rr) {
        int r = row0 + ty * 8 + rr;
        if (r >= NN) continue;
        float s = (fmode == 0) ? dinv[r] : 1.0f;
        #pragma unroll
        for (int cc = 0; cc < 8; ++cc) {
            int col = col0 + tx * 8 + cc;
            if (col >= Mpad) continue;
            float v = 0.0f;
            if (col < M) {
                v = acc[rr][cc] + bias[col];
                v = fmode ? (1.0f / (1.0f + expf(-v))) : fmaxf(v, 0.0f) * s;
            }
            if (fmode) ((float*)out)[(size_t)r * ostride + col] = v;          // FINAL: fp32
            else if (sf) ((float*)out)[(size_t)r * ostride + col] = v;
            else ((unsigned short*)out)[(size_t)r * ostride + col] = f2bf(v);
        }
    }
}

__global__ void k_sentinel(float* __restrict__ out, int n) {
    int i = blockIdx.x * blockDim.x + threadIdx.x;
    if (i < n) out[i] = 4.0f;
}

extern "C" void kernel_launch(void* const* d_in, const int* in_sizes, int n_in,
                              void* d_out, int out_size, void* d_ws, size_t ws_size,
                              hipStream_t stream) {
    const int* ei = (const int*)d_in[1];
    float* out_e = (float*)d_out;                     // fp32 [N,256]
    float* out_v = out_e + (size_t)NN * 256;          // fp32 [N,128]

    const int wsz[16] = {128 * 166, 166, 166 * 192, 192, 192 * 218, 218, 218 * 256, 256,
                         128 * 128, 128, 128 * 128, 128, 128 * 128, 128, 128 * 128, 128};
    PTab tab;
    tab.p[0] = d_in[0]; tab.n[0] = NN * 128; tab.o[0] = 0;
    int wacc = 0;
    for (int t = 0; t < 16; ++t) {
        tab.p[t + 1] = d_in[2 + t];
        tab.n[t + 1] = wsz[t];
        tab.o[t + 1] = wacc;
        wacc += wsz[t];
    }

    // ---- explicit workspace layout ----
    char* wsb = (char*)d_ws;
    size_t o = 0;
    int*   flags  = (int*)(wsb + o);  o = (o + 128 + 255) & ~(size_t)255;
    int*   src32  = (int*)(wsb + o);  o = (o + (size_t)NE * 4 + 255) & ~(size_t)255;
    int*   dst32  = (int*)(wsb + o);  o = (o + (size_t)NE * 4 + 255) & ~(size_t)255;
    int*   colv   = (int*)(wsb + o);  o = (o + (size_t)NE * 4 + 255) & ~(size_t)255;
    int*   deg    = (int*)(wsb + o);  o = (o + (size_t)NN * 4 + 255) & ~(size_t)255;
    int*   cursor = (int*)(wsb + o);  o = (o + (size_t)NN * 4 + 255) & ~(size_t)255;
    int*   rowp   = (int*)(wsb + o);  o = (o + (size_t)(NN + 1) * 4 + 255) & ~(size_t)255;
    int*   part   = (int*)(wsb + o);  o = (o + 512 + 255) & ~(size_t)255;
    float* dinv   = (float*)(wsb + o); o = (o + (size_t)NN * 4 + 255) & ~(size_t)255;
    float* wflat  = (float*)(wsb + o); o = (o + (size_t)wacc * 4 + 255) & ~(size_t)255;
    size_t F = o;
    size_t big = (size_t)NN * (128 + SW + SW);
    int sf;
    if (ws_size >= F + big * 4) sf = 1;          // fp32 intermediates
    else if (ws_size >= F + big * 2) sf = 0;     // bf16 intermediates
    else {
        k_sentinel<<<(out_size + 255) / 256, 256, 0, stream>>>(out_e, out_size);
        return;
    }
    size_t es = sf ? 4 : 2;
    void* aggX1 = (void*)(wsb + F);
    void* bufA  = (void*)(wsb + F + (size_t)NN * 128 * es);
    void* bufB  = (void*)(wsb + F + (size_t)NN * (128 + SW) * es);

    const int EB = (NE + 255) / 256;
    const int NB512 = (NN + 511) / 512;
    const int GX = (NN + GBM - 1) / GBM;

    // ---- probes + conversion ----
    k_probe<<<1, 256, 0, stream>>>(tab, ei, flags);
    k_wconv<<<256, 256, 0, stream>>>(tab, flags, wflat);

    // ---- CSR / norm ----
    k_repack<<<EB, 256, 0, stream>>>(ei, flags, src32, dst32);
    k_zero<<<(NN + 255) / 256, 256, 0, stream>>>(deg, NN);
    k_zero<<<(NN + 255) / 256, 256, 0, stream>>>(cursor, NN);
    k_count<<<EB, 256, 0, stream>>>(dst32, deg);
    k_scan1<<<NB512, 512, 0, stream>>>(deg, rowp, part);
    k_scan2<<<1, 128, 0, stream>>>(part, NB512);
    k_scan3<<<(NN + 255) / 256, 256, 0, stream>>>(rowp, part, deg, dinv);
    k_fill<<<EB, 256, 0, stream>>>(src32, dst32, rowp, cursor, colv);

    // ---- shared first aggregation ----
    k_xin<<<(NN * 16 + 255) / 256, 256, 0, stream>>>(d_in[0], flags, dinv, bufA, sf);
    k_gather<<<(NN + 3) / 4, 256, 0, stream>>>(bufA, SW, aggX1, 128, 16, rowp, colv, dinv, sf);

    // ---- e branch: 128 -> 166 -> 192 -> 218 -> 256 ----
    k_gemm<<<dim3(GX, 2), 256, 0, stream>>>(aggX1, 128, wflat + tab.o[1], wflat + tab.o[2],
                                            dinv, bufA, SW, 128, 166, 176, sf, 0);
    k_gather<<<(NN + 3) / 4, 256, 0, stream>>>(bufA, SW, bufB, SW, 22, rowp, colv, dinv, sf);
    k_gemm<<<dim3(GX, 2), 256, 0, stream>>>(bufB, SW, wflat + tab.o[3], wflat + tab.o[4],
                                            dinv, bufA, SW, 166, 192, 192, sf, 0);
    k_gather<<<(NN + 3) / 4, 256, 0, stream>>>(bufA, SW, bufB, SW, 24, rowp, colv, dinv, sf);
    k_gemm<<<dim3(GX, 2), 256, 0, stream>>>(bufB, SW, wflat + tab.o[5], wflat + tab.o[6],
                                            dinv, bufA, SW, 192, 218, 224, sf, 0);
    k_gather<<<(NN + 3) / 4, 256, 0, stream>>>(bufA, SW, bufB, SW, 28, rowp, colv, dinv, sf);
    k_gemm<<<dim3(GX, 2), 256, 0, stream>>>(bufB, SW, wflat + tab.o[7], wflat + tab.o[8],
                                            nullptr, out_e, 256, 218, 256, 256, sf, 1);

    // ---- n branch: 128 x4 ----
    k_gemm<<<dim3(GX, 1), 256, 0, stream>>>(aggX1, 128, wflat + tab.o[9], wflat + tab.o[10],
                                            dinv, bufA, SW, 128, 128, 128, sf, 0);
    k_gather<<<(NN + 3) / 4, 256, 0, stream>>>(bufA, SW, bufB, SW, 16, rowp, colv, dinv, sf);
    k_gemm<<<dim3(GX, 1), 256, 0, stream>>>(bufB, SW, wflat + tab.o[11], wflat + tab.o[12],
                                            dinv, bufA, SW, 128, 128, 128, sf, 0);
    k_gather<<<(NN + 3) / 4, 256, 0, stream>>>(bufA, SW, bufB, SW, 16, rowp, colv, dinv, sf);
    k_gemm<<<dim3(GX, 1), 256, 0, stream>>>(bufB, SW, wflat + tab.o[13], wflat + tab.o[14],
                                            dinv, bufA, SW, 128, 128, 128, sf, 0);
    k_gather<<<(NN + 3) / 4, 256, 0, stream>>>(bufA, SW, bufB, SW, 16, rowp, colv, dinv, sf);
    k_gemm<<<dim3(GX, 1), 256, 0, stream>>>(bufB, SW, wflat + tab.o[15], wflat + tab.o[16],
                                            nullptr, out_v, 128, 128, 128, 128, sf, 1);
}

// Round 6
// 980.733 us; speedup vs baseline: 1.3792x; 1.3792x over previous
//
#include <hip/hip_runtime.h>
#include <hip/hip_bf16.h>
#include <cstdint>
#include <cstddef>

typedef __hip_bfloat16 bf16;
typedef __attribute__((ext_vector_type(8))) short bf16x8;
typedef __attribute__((ext_vector_type(4))) float f32x4;

#define NN 50000
#define NE 400000
#define SW 224   // fp32 intermediate row stride (elements)

struct PTab {
    const void* p[17];
    int n[17];
};

__device__ __forceinline__ float bf2f(unsigned short u) {
    return __uint_as_float(((unsigned)u) << 16);
}
__device__ __forceinline__ unsigned short f2bf(float f) {
    __hip_bfloat16 h = __float2bfloat16(f);
    return *reinterpret_cast<unsigned short*>(&h);
}
__device__ __forceinline__ float fin(float v) {
    return (v == v && v > -1e30f && v < 1e30f) ? v : 0.0f;
}
__device__ __forceinline__ float rd(const void* p, int i, int f) {
    return f ? ((const float*)p)[i] : bf2f(((const unsigned short*)p)[i]);
}

// ---- probe dtypes: flags[t]=1 if tensor t is fp32, 0 if bf16 (t=0..16);
// flags[17]=1 if edge_index is int32 layout, 0 if int64 ----
__global__ void k_probe(PTab tab, const int* __restrict__ ei, int* __restrict__ flags) {
    __shared__ int zc, bc, sAny;
    for (int t = 0; t < 17; ++t) {
        if (threadIdx.x == 0) { zc = 0; bc = 0; }
        __syncthreads();
        int words = tab.n[t] >> 1;
        if (words > 256) words = 256;
        if ((int)threadIdx.x < words) {
            unsigned w = ((const unsigned*)tab.p[t])[threadIdx.x];
            if (w == 0u) atomicAdd(&zc, 1);
            else {
                int e = (w >> 7) & 0xFF;
                if (e >= 100 && e <= 140) atomicAdd(&bc, 1);
            }
        }
        __syncthreads();
        if (threadIdx.x == 0) {
            int nz = words - zc;
            flags[t] = (nz == 0 || 2 * bc >= nz) ? 0 : 1;
        }
        __syncthreads();
    }
    if (threadIdx.x == 0) sAny = 0;
    __syncthreads();
    int any = 0;
    for (int i = threadIdx.x; i < 2048; i += 256) any |= ei[2 * i + 1];
    if (any) sAny = 1;
    __syncthreads();
    if (threadIdx.x == 0) flags[17] = sAny;
}

// ---- split W into transposed bf16 hi/lo: wh/wl [Mp128][Kp], zero-padded ----
__global__ void k_wsplit(const void* __restrict__ W, const int* __restrict__ flags, int fidx,
                         int K, int M, int Kp,
                         unsigned short* __restrict__ wh, unsigned short* __restrict__ wl) {
    int n = blockIdx.x;          // output col (0..Mp128-1)
    int k = threadIdx.x;
    if (k >= Kp) return;
    float v = 0.0f;
    if (k < K && n < M) v = fin(rd(W, k * M + n, flags[fidx]));
    unsigned short hi = f2bf(v);
    unsigned short lo = f2bf(v - bf2f(hi));
    wh[(size_t)n * Kp + k] = hi;
    wl[(size_t)n * Kp + k] = lo;
}

__global__ void k_bias(const void* __restrict__ b, const int* __restrict__ flags, int fidx,
                       int M, float* __restrict__ dst) {
    int i = threadIdx.x;
    if (i < M) dst[i] = fin(rd(b, i, flags[fidx]));
}

__global__ void k_repack(const int* __restrict__ ei, const int* __restrict__ flags,
                         int* __restrict__ src, int* __restrict__ dst) {
    int e = blockIdx.x * blockDim.x + threadIdx.x;
    if (e >= NE) return;
    int s, d;
    if (flags[17]) { s = ei[e]; d = ei[NE + e]; }
    else           { s = ei[2 * e]; d = ei[2 * (NE + e)]; }
    src[e] = min(max(s, 0), NN - 1);
    dst[e] = min(max(d, 0), NN - 1);
}

__global__ void k_zero(int* __restrict__ p, int n) {
    int i = blockIdx.x * blockDim.x + threadIdx.x;
    if (i < n) p[i] = 0;
}

__global__ void k_count(const int* __restrict__ dst, int* __restrict__ deg) {
    int e = blockIdx.x * blockDim.x + threadIdx.x;
    if (e < NE) atomicAdd(&deg[dst[e]], 1);
}

__global__ void k_scan1(const int* __restrict__ deg, int* __restrict__ rowp,
                        int* __restrict__ part) {
    __shared__ int s[512];
    int tid = threadIdx.x, i = blockIdx.x * 512 + tid;
    int v = (i < NN) ? deg[i] : 0;
    s[tid] = v;
    __syncthreads();
    for (int off = 1; off < 512; off <<= 1) {
        int t = (tid >= off) ? s[tid - off] : 0;
        __syncthreads();
        s[tid] += t;
        __syncthreads();
    }
    if (i < NN) rowp[i] = s[tid] - v;
    if (tid == 511) part[blockIdx.x] = s[511];
}
__global__ void k_scan2(int* __restrict__ part, int nb) {
    __shared__ int s[128];
    int tid = threadIdx.x;
    int v = (tid < nb) ? part[tid] : 0;
    s[tid] = v;
    __syncthreads();
    for (int off = 1; off < 128; off <<= 1) {
        int t = (tid >= off) ? s[tid - off] : 0;
        __syncthreads();
        s[tid] += t;
        __syncthreads();
    }
    if (tid < nb) part[tid] = s[tid] - v;
}
__global__ void k_scan3(int* __restrict__ rowp, const int* __restrict__ part,
                        const int* __restrict__ deg, float* __restrict__ dinv) {
    int i = blockIdx.x * blockDim.x + threadIdx.x;
    if (i < NN) {
        rowp[i] += part[i >> 9];
        dinv[i] = rsqrtf((float)deg[i] + 1.0f);
    }
    if (i == 0) rowp[NN] = NE;
}

__global__ void k_fill(const int* __restrict__ src, const int* __restrict__ dst,
                       const int* __restrict__ rowp, int* __restrict__ cursor,
                       int* __restrict__ colv) {
    int e = blockIdx.x * blockDim.x + threadIdx.x;
    if (e >= NE) return;
    int d = dst[e];
    int p = atomicAdd(&cursor[d], 1);
    colv[rowp[d] + p] = src[e];
}

// ---- bufA = x * dinv (fp32, stride SW) ----
__global__ void k_xin(const void* __restrict__ x, const int* __restrict__ flags,
                      const float* __restrict__ dinv, float* __restrict__ bufA) {
    int t = blockIdx.x * blockDim.x + threadIdx.x;
    if (t >= NN * 16) return;
    int i = t >> 4, c = (t & 15) * 8;
    float d = dinv[i];
    float* o = bufA + (size_t)i * SW + c;
    int f = flags[0];
    const float* xf = (const float*)x + (size_t)i * 128 + c;
    const unsigned short* xb = (const unsigned short*)x + (size_t)i * 128 + c;
    #pragma unroll
    for (int j = 0; j < 8; ++j)
        o[j] = fin(f ? xf[j] : bf2f(xb[j])) * d;
}

// ---- CSR gather (fp32): out[i] = dinv[i] * (in[i] + sum_j in[colv[j]]) ----
__global__ void k_gather(const float* __restrict__ in, int istride,
                         float* __restrict__ out, int ostride, int kpad8,
                         const int* __restrict__ rowp, const int* __restrict__ colv,
                         const float* __restrict__ dinv) {
    int node = blockIdx.x * 4 + (threadIdx.x >> 6);
    int lane = threadIdx.x & 63;
    if (node >= NN) return;
    bool on = lane < kpad8;
    float a[8] = {};
    const int beg = rowp[node], end = rowp[node + 1];
    if (on) {
        const float* p = in + (size_t)node * istride + lane * 8;
        #pragma unroll
        for (int j = 0; j < 8; ++j) a[j] = p[j];
    }
    for (int j = beg; j < end; ++j) {
        int s = colv[j];
        if (on) {
            const float* p = in + (size_t)s * istride + lane * 8;
            #pragma unroll
            for (int t = 0; t < 8; ++t) a[t] += p[t];
        }
    }
    if (on) {
        float d = dinv[node];
        float* o = out + (size_t)node * ostride + lane * 8;
        #pragma unroll
        for (int j = 0; j < 8; ++j) o[j] = a[j] * d;
    }
}

// ---- MFMA GEMM, split-bf16 3-term (fp32-accurate) ----
// out = post(A @ W + b). A fp32 [N,astride]; W pre-split/transposed bf16 [Mp128][Kp].
// act=0: relu * dinv[row], write fp32 cols<OutW (0 beyond M). act=1: sigmoid, final.
__launch_bounds__(256)
__global__ void k_mgemm(const float* __restrict__ A, int astride,
                        const unsigned short* __restrict__ Wh,
                        const unsigned short* __restrict__ Wl, int Kp,
                        const float* __restrict__ bias, const float* __restrict__ dinv,
                        float* __restrict__ out, int ostride, int M, int OutW, int act) {
    __shared__ unsigned short sAh[128][40];
    __shared__ unsigned short sAl[128][40];
    __shared__ unsigned short sBh[128][40];
    __shared__ unsigned short sBl[128][40];
    const int tid = threadIdx.x;
    const int wave = tid >> 6, lane = tid & 63;
    const int wr = wave >> 1, wc = wave & 1;
    const int quad = lane >> 4, m16 = lane & 15;
    const int row0 = blockIdx.x * 128, col0 = blockIdx.y * 128;

    f32x4 zz = {0.f, 0.f, 0.f, 0.f};
    f32x4 acc[4][4];
    #pragma unroll
    for (int i = 0; i < 4; ++i)
        #pragma unroll
        for (int j = 0; j < 4; ++j) acc[i][j] = zz;

    const int sr = tid >> 1;             // staging row 0..127
    const int sh = (tid & 1) * 16;       // k offset 0/16
    int arow = row0 + sr; if (arow >= NN) arow = NN - 1;
    const float* aptr = A + (size_t)arow * astride + sh;
    const unsigned short* bhp = Wh + (size_t)(col0 + sr) * Kp + sh;
    const unsigned short* blp = Wl + (size_t)(col0 + sr) * Kp + sh;

    for (int k0 = 0; k0 < Kp; k0 += 32) {
        // ---- stage A (split fp32 -> hi/lo bf16) ----
        {
            float fv[16];
            *(float4*)&fv[0]  = *(const float4*)(aptr + k0);
            *(float4*)&fv[4]  = *(const float4*)(aptr + k0 + 4);
            *(float4*)&fv[8]  = *(const float4*)(aptr + k0 + 8);
            *(float4*)&fv[12] = *(const float4*)(aptr + k0 + 12);
            unsigned short hi[16], lo[16];
            #pragma unroll
            for (int j = 0; j < 16; ++j) {
                hi[j] = f2bf(fv[j]);
                lo[j] = f2bf(fv[j] - bf2f(hi[j]));
            }
            *(uint4*)&sAh[sr][sh]     = *(uint4*)&hi[0];
            *(uint4*)&sAh[sr][sh + 8] = *(uint4*)&hi[8];
            *(uint4*)&sAl[sr][sh]     = *(uint4*)&lo[0];
            *(uint4*)&sAl[sr][sh + 8] = *(uint4*)&lo[8];
        }
        // ---- stage B (pre-split bf16, direct copy) ----
        {
            uint4 u0 = *(const uint4*)(bhp + k0);
            uint4 u1 = *(const uint4*)(bhp + k0 + 8);
            *(uint4*)&sBh[sr][sh]     = u0;
            *(uint4*)&sBh[sr][sh + 8] = u1;
            uint4 v0 = *(const uint4*)(blp + k0);
            uint4 v1 = *(const uint4*)(blp + k0 + 8);
            *(uint4*)&sBl[sr][sh]     = v0;
            *(uint4*)&sBl[sr][sh + 8] = v1;
        }
        __syncthreads();
        bf16x8 ah[4], al[4], bh[4], bl[4];
        #pragma unroll
        for (int i = 0; i < 4; ++i) {
            ah[i] = *(const bf16x8*)&sAh[wr * 64 + i * 16 + m16][quad * 8];
            al[i] = *(const bf16x8*)&sAl[wr * 64 + i * 16 + m16][quad * 8];
            bh[i] = *(const bf16x8*)&sBh[wc * 64 + i * 16 + m16][quad * 8];
            bl[i] = *(const bf16x8*)&sBl[wc * 64 + i * 16 + m16][quad * 8];
        }
        #pragma unroll
        for (int i = 0; i < 4; ++i)
            #pragma unroll
            for (int j = 0; j < 4; ++j) {
                acc[i][j] = __builtin_amdgcn_mfma_f32_16x16x32_bf16(ah[i], bh[j], acc[i][j], 0, 0, 0);
                acc[i][j] = __builtin_amdgcn_mfma_f32_16x16x32_bf16(ah[i], bl[j], acc[i][j], 0, 0, 0);
                acc[i][j] = __builtin_amdgcn_mfma_f32_16x16x32_bf16(al[i], bh[j], acc[i][j], 0, 0, 0);
            }
        __syncthreads();
    }

    // ---- epilogue: C/D layout col=lane&15, row=quad*4+reg ----
    #pragma unroll
    for (int j = 0; j < 4; ++j) {
        int col = col0 + wc * 64 + j * 16 + m16;
        if (col >= OutW) continue;
        float bcol = (col < M) ? bias[col] : 0.0f;
        #pragma unroll
        for (int i = 0; i < 4; ++i) {
            #pragma unroll
            for (int r = 0; r < 4; ++r) {
                int row = row0 + wr * 64 + i * 16 + quad * 4 + r;
                if (row >= NN) continue;
                float v = 0.0f;
                if (col < M) {
                    float z = acc[i][j][r] + bcol;
                    v = act ? (1.0f / (1.0f + expf(-z))) : fmaxf(z, 0.0f) * dinv[row];
                }
                out[(size_t)row * ostride + col] = v;
            }
        }
    }
}

__global__ void k_sentinel(float* __restrict__ out, int n) {
    int i = blockIdx.x * blockDim.x + threadIdx.x;
    if (i < n) out[i] = 4.0f;
}

extern "C" void kernel_launch(void* const* d_in, const int* in_sizes, int n_in,
                              void* d_out, int out_size, void* d_ws, size_t ws_size,
                              hipStream_t stream) {
    const int* ei = (const int*)d_in[1];
    float* out_e = (float*)d_out;                     // fp32 [N,256]
    float* out_v = out_e + (size_t)NN * 256;          // fp32 [N,128]

    const int wsz[16] = {128 * 166, 166, 166 * 192, 192, 192 * 218, 218, 218 * 256, 256,
                         128 * 128, 128, 128 * 128, 128, 128 * 128, 128, 128 * 128, 128};
    PTab tab;
    tab.p[0] = d_in[0]; tab.n[0] = NN * 128;
    for (int t = 0; t < 16; ++t) { tab.p[t + 1] = d_in[2 + t]; tab.n[t + 1] = wsz[t]; }

    // layer tables: l=0..3 e-branch, 4..7 n-branch
    const int Ksrc[8] = {128, 166, 192, 218, 128, 128, 128, 128};
    const int Kp[8]   = {128, 192, 192, 224, 128, 128, 128, 128};
    const int Mm[8]   = {166, 192, 218, 256, 128, 128, 128, 128};
    const int Mp[8]   = {256, 256, 256, 256, 128, 128, 128, 128};
    const int OutW[8] = {192, 192, 224, 256, 128, 128, 128, 128};

    // ---- workspace layout ----
    char* wsb = (char*)d_ws;
    size_t o = 0;
    auto align = [](size_t v) { return (v + 255) & ~(size_t)255; };
    int*   flags  = (int*)(wsb + o);  o = align(o + 128);
    int*   src32  = (int*)(wsb + o);  o = align(o + (size_t)NE * 4);
    int*   dst32  = (int*)(wsb + o);  o = align(o + (size_t)NE * 4);
    int*   colv   = (int*)(wsb + o);  o = align(o + (size_t)NE * 4);
    int*   deg    = (int*)(wsb + o);  o = align(o + (size_t)NN * 4);
    int*   cursor = (int*)(wsb + o);  o = align(o + (size_t)NN * 4);
    int*   rowp   = (int*)(wsb + o);  o = align(o + (size_t)(NN + 1) * 4);
    int*   part   = (int*)(wsb + o);  o = align(o + 512);
    float* dinv   = (float*)(wsb + o); o = align(o + (size_t)NN * 4);
    unsigned short* wh[8]; unsigned short* wl[8]; float* bs[8];
    for (int l = 0; l < 8; ++l) {
        size_t wel = (size_t)Mp[l] * Kp[l];
        wh[l] = (unsigned short*)(wsb + o); o = align(o + wel * 2);
        wl[l] = (unsigned short*)(wsb + o); o = align(o + wel * 2);
        bs[l] = (float*)(wsb + o);          o = align(o + (size_t)Mm[l] * 4);
    }
    float* aggX1 = (float*)(wsb + o); o = align(o + (size_t)NN * 128 * 4);
    float* bufA  = (float*)(wsb + o); o = align(o + (size_t)NN * SW * 4);
    float* bufB  = (float*)(wsb + o); o = align(o + (size_t)NN * SW * 4);
    if (o > ws_size) {
        k_sentinel<<<(out_size + 255) / 256, 256, 0, stream>>>(out_e, out_size);
        return;
    }

    const int EB = (NE + 255) / 256;
    const int NB512 = (NN + 511) / 512;
    const int GX = (NN + 127) / 128;   // 391

    // ---- probes + weight split/transpose + biases ----
    k_probe<<<1, 256, 0, stream>>>(tab, ei, flags);
    for (int l = 0; l < 8; ++l) {
        k_wsplit<<<Mp[l], 256, 0, stream>>>(d_in[2 + 2 * l], flags, 1 + 2 * l,
                                            Ksrc[l], Mm[l], Kp[l], wh[l], wl[l]);
        k_bias<<<1, 256, 0, stream>>>(d_in[3 + 2 * l], flags, 2 + 2 * l, Mm[l], bs[l]);
    }

    // ---- CSR / norm ----
    k_repack<<<EB, 256, 0, stream>>>(ei, flags, src32, dst32);
    k_zero<<<(NN + 255) / 256, 256, 0, stream>>>(deg, NN);
    k_zero<<<(NN + 255) / 256, 256, 0, stream>>>(cursor, NN);
    k_count<<<EB, 256, 0, stream>>>(dst32, deg);
    k_scan1<<<NB512, 512, 0, stream>>>(deg, rowp, part);
    k_scan2<<<1, 128, 0, stream>>>(part, NB512);
    k_scan3<<<(NN + 255) / 256, 256, 0, stream>>>(rowp, part, deg, dinv);
    k_fill<<<EB, 256, 0, stream>>>(src32, dst32, rowp, cursor, colv);

    // ---- shared first aggregation ----
    k_xin<<<(NN * 16 + 255) / 256, 256, 0, stream>>>(d_in[0], flags, dinv, bufA);
    k_gather<<<(NN + 3) / 4, 256, 0, stream>>>(bufA, SW, aggX1, 128, 16, rowp, colv, dinv);

    const int GN = (NN + 3) / 4;
    // ---- e branch ----
    k_mgemm<<<dim3(GX, 2), 256, 0, stream>>>(aggX1, 128, wh[0], wl[0], Kp[0], bs[0], dinv,
                                             bufA, SW, Mm[0], OutW[0], 0);
    k_gather<<<GN, 256, 0, stream>>>(bufA, SW, bufB, SW, OutW[0] / 8, rowp, colv, dinv);
    k_mgemm<<<dim3(GX, 2), 256, 0, stream>>>(bufB, SW, wh[1], wl[1], Kp[1], bs[1], dinv,
                                             bufA, SW, Mm[1], OutW[1], 0);
    k_gather<<<GN, 256, 0, stream>>>(bufA, SW, bufB, SW, OutW[1] / 8, rowp, colv, dinv);
    k_mgemm<<<dim3(GX, 2), 256, 0, stream>>>(bufB, SW, wh[2], wl[2], Kp[2], bs[2], dinv,
                                             bufA, SW, Mm[2], OutW[2], 0);
    k_gather<<<GN, 256, 0, stream>>>(bufA, SW, bufB, SW, OutW[2] / 8, rowp, colv, dinv);
    k_mgemm<<<dim3(GX, 2), 256, 0, stream>>>(bufB, SW, wh[3], wl[3], Kp[3], bs[3], dinv,
                                             out_e, 256, Mm[3], OutW[3], 1);

    // ---- n branch ----
    k_mgemm<<<dim3(GX, 1), 256, 0, stream>>>(aggX1, 128, wh[4], wl[4], Kp[4], bs[4], dinv,
                                             bufA, SW, Mm[4], OutW[4], 0);
    k_gather<<<GN, 256, 0, stream>>>(bufA, SW, bufB, SW, 16, rowp, colv, dinv);
    k_mgemm<<<dim3(GX, 1), 256, 0, stream>>>(bufB, SW, wh[5], wl[5], Kp[5], bs[5], dinv,
                                             bufA, SW, Mm[5], OutW[5], 0);
    k_gather<<<GN, 256, 0, stream>>>(bufA, SW, bufB, SW, 16, rowp, colv, dinv);
    k_mgemm<<<dim3(GX, 1), 256, 0, stream>>>(bufB, SW, wh[6], wl[6], Kp[6], bs[6], dinv,
                                             bufA, SW, Mm[6], OutW[6], 0);
    k_gather<<<GN, 256, 0, stream>>>(bufA, SW, bufB, SW, 16, rowp, colv, dinv);
    k_mgemm<<<dim3(GX, 1), 256, 0, stream>>>(bufB, SW, wh[7], wl[7], Kp[7], bs[7], dinv,
                                             out_v, 128, Mm[7], OutW[7], 1);
}

// Round 7
// 711.931 us; speedup vs baseline: 1.9000x; 1.3776x over previous
//
#include <hip/hip_runtime.h>
#include <hip/hip_bf16.h>
#include <cstdint>
#include <cstddef>

typedef __hip_bfloat16 bf16;
typedef __attribute__((ext_vector_type(8))) short bf16x8;
typedef __attribute__((ext_vector_type(4))) float f32x4;

#define NN 50000
#define NE 400000
#define SWB 224   // bf16 intermediate row stride (elements)

struct PTab {
    const void* p[17];
    int n[17];
};

__device__ __forceinline__ float bf2f(unsigned short u) {
    return __uint_as_float(((unsigned)u) << 16);
}
__device__ __forceinline__ unsigned short f2bf(float f) {
    __hip_bfloat16 h = __float2bfloat16(f);
    return *reinterpret_cast<unsigned short*>(&h);
}
__device__ __forceinline__ float fin(float v) {
    return (v == v && v > -1e30f && v < 1e30f) ? v : 0.0f;
}
__device__ __forceinline__ float rd(const void* p, int i, int f) {
    return f ? ((const float*)p)[i] : bf2f(((const unsigned short*)p)[i]);
}

// ---- probe dtypes: flags[t]=1 fp32 / 0 bf16 (t=0..16); flags[17]=1 int32 ei ----
__global__ void k_probe(PTab tab, const int* __restrict__ ei, int* __restrict__ flags) {
    __shared__ int zc, bc, sAny;
    for (int t = 0; t < 17; ++t) {
        if (threadIdx.x == 0) { zc = 0; bc = 0; }
        __syncthreads();
        int words = tab.n[t] >> 1;
        if (words > 256) words = 256;
        if ((int)threadIdx.x < words) {
            unsigned w = ((const unsigned*)tab.p[t])[threadIdx.x];
            if (w == 0u) atomicAdd(&zc, 1);
            else {
                int e = (w >> 7) & 0xFF;
                if (e >= 100 && e <= 140) atomicAdd(&bc, 1);
            }
        }
        __syncthreads();
        if (threadIdx.x == 0) {
            int nz = words - zc;
            flags[t] = (nz == 0 || 2 * bc >= nz) ? 0 : 1;
        }
        __syncthreads();
    }
    if (threadIdx.x == 0) sAny = 0;
    __syncthreads();
    int any = 0;
    for (int i = threadIdx.x; i < 2048; i += 256) any |= ei[2 * i + 1];
    if (any) sAny = 1;
    __syncthreads();
    if (threadIdx.x == 0) flags[17] = sAny;
}

// ---- split W into transposed bf16 hi/lo: [Mp128][Kp], zero-padded ----
__global__ void k_wsplit(const void* __restrict__ W, const int* __restrict__ flags, int fidx,
                         int K, int M, int Kp,
                         unsigned short* __restrict__ wh, unsigned short* __restrict__ wl) {
    int n = blockIdx.x;
    int k = threadIdx.x;
    if (k >= Kp) return;
    float v = 0.0f;
    if (k < K && n < M) v = fin(rd(W, k * M + n, flags[fidx]));
    unsigned short hi = f2bf(v);
    unsigned short lo = f2bf(v - bf2f(hi));
    wh[(size_t)n * Kp + k] = hi;
    wl[(size_t)n * Kp + k] = lo;
}

struct MOff { int m[8]; };

// ---- all 8 biases in one launch: blockIdx = layer ----
__global__ void k_biasall(PTab tab, const int* __restrict__ flags, MOff mo,
                          float* __restrict__ dst) {
    int l = blockIdx.x;
    int fidx = 2 + 2 * l;
    int M = tab.n[fidx];
    int i = threadIdx.x;
    if (i < M) dst[mo.m[l] + i] = fin(rd(tab.p[fidx], i, flags[fidx]));
}

__global__ void k_repack(const int* __restrict__ ei, const int* __restrict__ flags,
                         int* __restrict__ src, int* __restrict__ dst) {
    int e = blockIdx.x * blockDim.x + threadIdx.x;
    if (e >= NE) return;
    int s, d;
    if (flags[17]) { s = ei[e]; d = ei[NE + e]; }
    else           { s = ei[2 * e]; d = ei[2 * (NE + e)]; }
    src[e] = min(max(s, 0), NN - 1);
    dst[e] = min(max(d, 0), NN - 1);
}

__global__ void k_zero2(int* __restrict__ a, int* __restrict__ b, int n) {
    int i = blockIdx.x * blockDim.x + threadIdx.x;
    if (i < n) { a[i] = 0; b[i] = 0; }
}

__global__ void k_count(const int* __restrict__ dst, int* __restrict__ deg) {
    int e = blockIdx.x * blockDim.x + threadIdx.x;
    if (e < NE) atomicAdd(&deg[dst[e]], 1);
}

__global__ void k_scan1(const int* __restrict__ deg, int* __restrict__ rowp,
                        int* __restrict__ part) {
    __shared__ int s[512];
    int tid = threadIdx.x, i = blockIdx.x * 512 + tid;
    int v = (i < NN) ? deg[i] : 0;
    s[tid] = v;
    __syncthreads();
    for (int off = 1; off < 512; off <<= 1) {
        int t = (tid >= off) ? s[tid - off] : 0;
        __syncthreads();
        s[tid] += t;
        __syncthreads();
    }
    if (i < NN) rowp[i] = s[tid] - v;
    if (tid == 511) part[blockIdx.x] = s[511];
}
__global__ void k_scan2(int* __restrict__ part, int nb) {
    __shared__ int s[128];
    int tid = threadIdx.x;
    int v = (tid < nb) ? part[tid] : 0;
    s[tid] = v;
    __syncthreads();
    for (int off = 1; off < 128; off <<= 1) {
        int t = (tid >= off) ? s[tid - off] : 0;
        __syncthreads();
        s[tid] += t;
        __syncthreads();
    }
    if (tid < nb) part[tid] = s[tid] - v;
}
__global__ void k_scan3(int* __restrict__ rowp, const int* __restrict__ part,
                        const int* __restrict__ deg, float* __restrict__ dinv) {
    int i = blockIdx.x * blockDim.x + threadIdx.x;
    if (i < NN) {
        rowp[i] += part[i >> 9];
        dinv[i] = rsqrtf((float)deg[i] + 1.0f);
    }
    if (i == 0) rowp[NN] = NE;
}

__global__ void k_fill(const int* __restrict__ src, const int* __restrict__ dst,
                       const int* __restrict__ rowp, int* __restrict__ cursor,
                       int* __restrict__ colv) {
    int e = blockIdx.x * blockDim.x + threadIdx.x;
    if (e >= NE) return;
    int d = dst[e];
    int p = atomicAdd(&cursor[d], 1);
    colv[rowp[d] + p] = src[e];
}

// ---- xs = bf16(x * dinv), stride 128 ----
__global__ void k_xin(const void* __restrict__ x, const int* __restrict__ flags,
                      const float* __restrict__ dinv, unsigned short* __restrict__ xs) {
    int t = blockIdx.x * blockDim.x + threadIdx.x;
    if (t >= NN * 16) return;
    int i = t >> 4, c = (t & 15) * 8;
    float d = dinv[i];
    int f = flags[0];
    const float* xf = (const float*)x + (size_t)i * 128 + c;
    const unsigned short* xb = (const unsigned short*)x + (size_t)i * 128 + c;
    unsigned short o[8];
    #pragma unroll
    for (int j = 0; j < 8; ++j)
        o[j] = f2bf(fin(f ? xf[j] : bf2f(xb[j])) * d);
    *(uint4*)(xs + (size_t)i * 128 + c) = *(uint4*)o;
}

// ---- CSR gather (bf16 in/out, fp32 accum): out[i]=dinv[i]*(in[i]+sum in[colv[j]]) ----
__global__ void k_gather(const unsigned short* __restrict__ in, int istride,
                         unsigned short* __restrict__ out, int ostride, int kpad8,
                         const int* __restrict__ rowp, const int* __restrict__ colv,
                         const float* __restrict__ dinv) {
    int node = blockIdx.x * 4 + (threadIdx.x >> 6);
    int lane = threadIdx.x & 63;
    if (node >= NN) return;
    bool on = lane < kpad8;
    float a[8] = {};
    const int beg = rowp[node], end = rowp[node + 1];
    if (on) {
        uint4 q = *(const uint4*)(in + (size_t)node * istride + lane * 8);
        unsigned v[4] = {q.x, q.y, q.z, q.w};
        #pragma unroll
        for (int t = 0; t < 4; ++t) { a[2 * t] = bf2f(v[t] & 0xFFFF); a[2 * t + 1] = bf2f(v[t] >> 16); }
    }
    int j = beg;
    for (; j + 1 < end; j += 2) {
        int s0 = colv[j], s1 = colv[j + 1];
        if (on) {
            uint4 q0 = *(const uint4*)(in + (size_t)s0 * istride + lane * 8);
            uint4 q1 = *(const uint4*)(in + (size_t)s1 * istride + lane * 8);
            unsigned v0[4] = {q0.x, q0.y, q0.z, q0.w};
            unsigned v1[4] = {q1.x, q1.y, q1.z, q1.w};
            #pragma unroll
            for (int t = 0; t < 4; ++t) {
                a[2 * t]     += bf2f(v0[t] & 0xFFFF) + bf2f(v1[t] & 0xFFFF);
                a[2 * t + 1] += bf2f(v0[t] >> 16)    + bf2f(v1[t] >> 16);
            }
        }
    }
    if (j < end) {
        int s = colv[j];
        if (on) {
            uint4 q = *(const uint4*)(in + (size_t)s * istride + lane * 8);
            unsigned v[4] = {q.x, q.y, q.z, q.w};
            #pragma unroll
            for (int t = 0; t < 4; ++t) {
                a[2 * t] += bf2f(v[t] & 0xFFFF); a[2 * t + 1] += bf2f(v[t] >> 16);
            }
        }
    }
    if (on) {
        float d = dinv[node];
        unsigned short o[8];
        #pragma unroll
        for (int t = 0; t < 8; ++t) o[t] = f2bf(a[t] * d);
        *(uint4*)(out + (size_t)node * ostride + lane * 8) = *(uint4*)o;
    }
}

// ---- MFMA GEMM, 2-term split (A bf16 exact, W hi/lo) ----
__launch_bounds__(256)
__global__ void k_mgemm(const unsigned short* __restrict__ A, int astride,
                        const unsigned short* __restrict__ Wh,
                        const unsigned short* __restrict__ Wl, int Kp,
                        const float* __restrict__ bias, const float* __restrict__ dinv,
                        void* __restrict__ out, int ostride, int M, int OutW, int act) {
    __shared__ unsigned short sA[128][40];
    __shared__ unsigned short sBh[128][40];
    __shared__ unsigned short sBl[128][40];
    const int tid = threadIdx.x;
    const int wave = tid >> 6, lane = tid & 63;
    const int wr = wave >> 1, wc = wave & 1;
    const int quad = lane >> 4, m16 = lane & 15;
    const int row0 = blockIdx.x * 128, col0 = blockIdx.y * 128;

    f32x4 zz = {0.f, 0.f, 0.f, 0.f};
    f32x4 acc[4][4];
    #pragma unroll
    for (int i = 0; i < 4; ++i)
        #pragma unroll
        for (int j = 0; j < 4; ++j) acc[i][j] = zz;

    const int sr = tid >> 1;
    const int sh = (tid & 1) * 16;
    int arow = row0 + sr; if (arow >= NN) arow = NN - 1;
    const unsigned short* aptr = A + (size_t)arow * astride + sh;
    const unsigned short* bhp = Wh + (size_t)(col0 + sr) * Kp + sh;
    const unsigned short* blp = Wl + (size_t)(col0 + sr) * Kp + sh;

    for (int k0 = 0; k0 < Kp; k0 += 32) {
        *(uint4*)&sA[sr][sh]      = *(const uint4*)(aptr + k0);
        *(uint4*)&sA[sr][sh + 8]  = *(const uint4*)(aptr + k0 + 8);
        *(uint4*)&sBh[sr][sh]     = *(const uint4*)(bhp + k0);
        *(uint4*)&sBh[sr][sh + 8] = *(const uint4*)(bhp + k0 + 8);
        *(uint4*)&sBl[sr][sh]     = *(const uint4*)(blp + k0);
        *(uint4*)&sBl[sr][sh + 8] = *(const uint4*)(blp + k0 + 8);
        __syncthreads();
        bf16x8 ah[4], bh[4], bl[4];
        #pragma unroll
        for (int i = 0; i < 4; ++i) {
            ah[i] = *(const bf16x8*)&sA[wr * 64 + i * 16 + m16][quad * 8];
            bh[i] = *(const bf16x8*)&sBh[wc * 64 + i * 16 + m16][quad * 8];
            bl[i] = *(const bf16x8*)&sBl[wc * 64 + i * 16 + m16][quad * 8];
        }
        #pragma unroll
        for (int i = 0; i < 4; ++i)
            #pragma unroll
            for (int j = 0; j < 4; ++j) {
                acc[i][j] = __builtin_amdgcn_mfma_f32_16x16x32_bf16(ah[i], bh[j], acc[i][j], 0, 0, 0);
                acc[i][j] = __builtin_amdgcn_mfma_f32_16x16x32_bf16(ah[i], bl[j], acc[i][j], 0, 0, 0);
            }
        __syncthreads();
    }

    #pragma unroll
    for (int j = 0; j < 4; ++j) {
        int col = col0 + wc * 64 + j * 16 + m16;
        if (col >= OutW) continue;
        float bcol = (col < M) ? bias[col] : 0.0f;
        #pragma unroll
        for (int i = 0; i < 4; ++i) {
            #pragma unroll
            for (int r = 0; r < 4; ++r) {
                int row = row0 + wr * 64 + i * 16 + quad * 4 + r;
                if (row >= NN) continue;
                if (act) {
                    float v = (col < M) ? 1.0f / (1.0f + expf(-(acc[i][j][r] + bcol))) : 0.0f;
                    ((float*)out)[(size_t)row * ostride + col] = v;
                } else {
                    float v = (col < M) ? fmaxf(acc[i][j][r] + bcol, 0.0f) * dinv[row] : 0.0f;
                    ((unsigned short*)out)[(size_t)row * ostride + col] = f2bf(v);
                }
            }
        }
    }
}

__global__ void k_sentinel(float* __restrict__ out, int n) {
    int i = blockIdx.x * blockDim.x + threadIdx.x;
    if (i < n) out[i] = 4.0f;
}

extern "C" void kernel_launch(void* const* d_in, const int* in_sizes, int n_in,
                              void* d_out, int out_size, void* d_ws, size_t ws_size,
                              hipStream_t stream) {
    const int* ei = (const int*)d_in[1];
    float* out_e = (float*)d_out;
    float* out_v = out_e + (size_t)NN * 256;

    const int wsz[16] = {128 * 166, 166, 166 * 192, 192, 192 * 218, 218, 218 * 256, 256,
                         128 * 128, 128, 128 * 128, 128, 128 * 128, 128, 128 * 128, 128};
    PTab tab;
    tab.p[0] = d_in[0]; tab.n[0] = NN * 128;
    for (int t = 0; t < 16; ++t) { tab.p[t + 1] = d_in[2 + t]; tab.n[t + 1] = wsz[t]; }

    const int Ksrc[8] = {128, 166, 192, 218, 128, 128, 128, 128};
    const int Kp[8]   = {128, 192, 192, 224, 128, 128, 128, 128};
    const int Mm[8]   = {166, 192, 218, 256, 128, 128, 128, 128};
    const int Mp[8]   = {256, 256, 256, 256, 128, 128, 128, 128};
    const int OutW[8] = {192, 192, 224, 256, 128, 128, 128, 128};

    char* wsb = (char*)d_ws;
    size_t o = 0;
    auto align = [](size_t v) { return (v + 255) & ~(size_t)255; };
    int*   flags  = (int*)(wsb + o);  o = align(o + 128);
    int*   src32  = (int*)(wsb + o);  o = align(o + (size_t)NE * 4);
    int*   dst32  = (int*)(wsb + o);  o = align(o + (size_t)NE * 4);
    int*   colv   = (int*)(wsb + o);  o = align(o + (size_t)NE * 4);
    int*   deg    = (int*)(wsb + o);  o = align(o + (size_t)NN * 4);
    int*   cursor = (int*)(wsb + o);  o = align(o + (size_t)NN * 4);
    int*   rowp   = (int*)(wsb + o);  o = align(o + (size_t)(NN + 1) * 4);
    int*   part   = (int*)(wsb + o);  o = align(o + 512);
    float* dinv   = (float*)(wsb + o); o = align(o + (size_t)NN * 4);
    unsigned short* wh[8]; unsigned short* wl[8];
    for (int l = 0; l < 8; ++l) {
        size_t wel = (size_t)Mp[l] * Kp[l];
        wh[l] = (unsigned short*)(wsb + o); o = align(o + wel * 2);
        wl[l] = (unsigned short*)(wsb + o); o = align(o + wel * 2);
    }
    MOff mo; float* ball = (float*)(wsb + o);
    { int a = 0; for (int l = 0; l < 8; ++l) { mo.m[l] = a; a += Mm[l]; } o = align(o + (size_t)a * 4); }
    unsigned short* aggX1 = (unsigned short*)(wsb + o); o = align(o + (size_t)NN * 128 * 2);
    unsigned short* bufA  = (unsigned short*)(wsb + o); o = align(o + (size_t)NN * SWB * 2);
    unsigned short* bufB  = (unsigned short*)(wsb + o); o = align(o + (size_t)NN * SWB * 2);
    if (o > ws_size) {
        k_sentinel<<<(out_size + 255) / 256, 256, 0, stream>>>(out_e, out_size);
        return;
    }

    const int EB = (NE + 255) / 256;
    const int NB512 = (NN + 511) / 512;
    const int GX = (NN + 127) / 128;
    const int GN = (NN + 3) / 4;

    k_probe<<<1, 256, 0, stream>>>(tab, ei, flags);
    for (int l = 0; l < 8; ++l)
        k_wsplit<<<Mp[l], 256, 0, stream>>>(d_in[2 + 2 * l], flags, 1 + 2 * l,
                                            Ksrc[l], Mm[l], Kp[l], wh[l], wl[l]);
    k_biasall<<<8, 256, 0, stream>>>(tab, flags, mo, ball);

    k_repack<<<EB, 256, 0, stream>>>(ei, flags, src32, dst32);
    k_zero2<<<(NN + 255) / 256, 256, 0, stream>>>(deg, cursor, NN);
    k_count<<<EB, 256, 0, stream>>>(dst32, deg);
    k_scan1<<<NB512, 512, 0, stream>>>(deg, rowp, part);
    k_scan2<<<1, 128, 0, stream>>>(part, NB512);
    k_scan3<<<(NN + 255) / 256, 256, 0, stream>>>(rowp, part, deg, dinv);
    k_fill<<<EB, 256, 0, stream>>>(src32, dst32, rowp, cursor, colv);

    k_xin<<<(NN * 16 + 255) / 256, 256, 0, stream>>>(d_in[0], flags, dinv, bufA);
    k_gather<<<GN, 256, 0, stream>>>(bufA, 128, aggX1, 128, 16, rowp, colv, dinv);

    float* bs[8];
    for (int l = 0; l < 8; ++l) bs[l] = ball + mo.m[l];

    k_mgemm<<<dim3(GX, 2), 256, 0, stream>>>(aggX1, 128, wh[0], wl[0], Kp[0], bs[0], dinv,
                                             bufA, SWB, Mm[0], OutW[0], 0);
    k_gather<<<GN, 256, 0, stream>>>(bufA, SWB, bufB, SWB, OutW[0] / 8, rowp, colv, dinv);
    k_mgemm<<<dim3(GX, 2), 256, 0, stream>>>(bufB, SWB, wh[1], wl[1], Kp[1], bs[1], dinv,
                                             bufA, SWB, Mm[1], OutW[1], 0);
    k_gather<<<GN, 256, 0, stream>>>(bufA, SWB, bufB, SWB, OutW[1] / 8, rowp, colv, dinv);
    k_mgemm<<<dim3(GX, 2), 256, 0, stream>>>(bufB, SWB, wh[2], wl[2], Kp[2], bs[2], dinv,
                                             bufA, SWB, Mm[2], OutW[2], 0);
    k_gather<<<GN, 256, 0, stream>>>(bufA, SWB, bufB, SWB, OutW[2] / 8, rowp, colv, dinv);
    k_mgemm<<<dim3(GX, 2), 256, 0, stream>>>(bufB, SWB, wh[3], wl[3], Kp[3], bs[3], dinv,
                                             out_e, 256, Mm[3], OutW[3], 1);

    k_mgemm<<<dim3(GX, 1), 256, 0, stream>>>(aggX1, 128, wh[4], wl[4], Kp[4], bs[4], dinv,
                                             bufA, SWB, Mm[4], OutW[4], 0);
    k_gather<<<GN, 256, 0, stream>>>(bufA, SWB, bufB, SWB, 16, rowp, colv, dinv);
    k_mgemm<<<dim3(GX, 1), 256, 0, stream>>>(bufB, SWB, wh[5], wl[5], Kp[5], bs[5], dinv,
                                             bufA, SWB, Mm[5], OutW[5], 0);
    k_gather<<<GN, 256, 0, stream>>>(bufA, SWB, bufB, SWB, 16, rowp, colv, dinv);
    k_mgemm<<<dim3(GX, 1), 256, 0, stream>>>(bufB, SWB, wh[6], wl[6], Kp[6], bs[6], dinv,
                                             bufA, SWB, Mm[6], OutW[6], 0);
    k_gather<<<GN, 256, 0, stream>>>(bufA, SWB, bufB, SWB, 16, rowp, colv, dinv);
    k_mgemm<<<dim3(GX, 1), 256, 0, stream>>>(bufB, SWB, wh[7], wl[7], Kp[7], bs[7], dinv,
                                             out_v, 128, Mm[7], OutW[7], 1);
}